// Round 4
// baseline (172.494 us; speedup 1.0000x reference)
//
#include <hip/hip_runtime.h>

typedef __attribute__((ext_vector_type(8))) short short8;
typedef __attribute__((ext_vector_type(4))) short short4v;
typedef __attribute__((ext_vector_type(4))) float float4v;

__device__ __forceinline__ short f2bf(float f) {
    union { float f; unsigned u; } v; v.f = f;
    return (short)((v.u + 0x7fffu + ((v.u >> 16) & 1u)) >> 16);
}

__device__ __forceinline__ float fast_exp2(float x) {
#if __has_builtin(__builtin_amdgcn_exp2f)
    return __builtin_amdgcn_exp2f(x);
#else
    return exp2f(x);
#endif
}

// pack two f32 -> one dword of 2 bf16 (low = lo, high = hi); no builtin on gfx950
__device__ __forceinline__ unsigned cvt_pk_bf16(float lo, float hi) {
    unsigned r;
    asm("v_cvt_pk_bf16_f32 %0, %1, %2" : "=v"(r) : "v"(lo), "v"(hi));
    return r;
}

// ---------------- kernel 0: weight transpose+convert (b-frag tiled) ---------
// Wt3T layout: 12 tiles p=j*4+nt (j: 0=Q,1=K,2=V; nt: n-16-tile), each tile
// [24 ksteps][64 lanes][8 shorts]: lane (l16,quad) slot i holds
// W_j[k=kstep*32+quad*8+i][n=nt*16+l16].  A wave's b-frag load is 1 KB contig.
__global__ void wtrans_kernel(const float* __restrict__ Wk, const float* __restrict__ Wq,
                              const float* __restrict__ Wv, short* __restrict__ Wt3T) {
    int idx = blockIdx.x * 256 + threadIdx.x;       // 3*64*768 = 147456
    int p = idx / 12288;                            // 12 tiles of 24*512
    int rem = idx - p * 12288;
    int kstep = rem / 512;
    int r2 = rem - kstep * 512;
    int lane = r2 >> 3, i = r2 & 7;
    int quad = lane >> 4, l16 = lane & 15;
    int j = p >> 2, nt = p & 3;
    int n = nt * 16 + l16;
    int k = kstep * 32 + quad * 8 + i;
    const float* W = (j == 0) ? Wq : (j == 1 ? Wk : Wv);
    // log2(e)/sqrt(768) folded into Wq -> scores arrive in log2 domain
    float scale = (j == 0) ? 0.05205877f : 1.0f;
    Wt3T[idx] = f2bf(W[k * 64 + n] * scale);
}

// ---------------- kernel 1: QKV projection, N-split, shared-A LDS -----------
// 1024 blocks x 16 rows. x tile staged+converted ONCE per block into LDS
// (A-layout, 3-slot rotation, one barrier/k-step). Wave w owns output tiles
// p=3w..3w+2; W-frags and x loads issued right after the barrier so the next
// barrier's vmcnt(0) drain completes them -> latency absorbed by the barrier.
// V is written to Vtr with the sigma column permutation (within 64-aligned
// s-blocks) so the attention kernel's PV A-fragments become lane-local.
__global__ __launch_bounds__(256, 4) void proj_kernel(
    const float* __restrict__ x, const short* __restrict__ Wt3T,
    short* __restrict__ Qs, short* __restrict__ Kb, short* __restrict__ Vtr)
{
    __shared__ alignas(16) int Abuf[3][256];        // 3 slots of [16 rows][32 k] bf16
    __shared__ alignas(16) short sm[16 * 72];       // V transpose staging
    const int tid = threadIdx.x;
    const int wave = tid >> 6, lane = tid & 63, quad = lane >> 4, l16 = lane & 15;
    const int m0 = blockIdx.x * 16;
    const int p0 = wave * 3;

    // x cooperative staging: thread -> 2 fp32 at (row = tid>>4, col = (tid&15)*2)
    const int xrow = tid >> 4, xcol = (tid & 15) * 2;
    const float* xp = x + (size_t)(m0 + xrow) * 768 + xcol;
    const int aidx = xrow * 16 + (tid & 15);
    // W: wave-private b-frag stream, tile t at (p0+t)*24*512, step at it*512
    const short* wt0 = Wt3T + (size_t)(p0 * 24) * 512 + lane * 8;

    float4v acc[3];
#pragma unroll
    for (int t = 0; t < 3; ++t) acc[t] = (float4v){0.f, 0.f, 0.f, 0.f};

    // prologue: A(0) direct, issue W(0), x(1)
    {
        float2 u = *(const float2*)xp;
        Abuf[0][aidx] = ((unsigned short)f2bf(u.x)) | ((unsigned)f2bf(u.y) << 16);
    }
    short8 Wc0 = *(const short8*)(wt0);
    short8 Wc1 = *(const short8*)(wt0 + 12288);
    short8 Wc2 = *(const short8*)(wt0 + 24576);
    float2 Xn = *(const float2*)(xp + 32);
    __syncthreads();        // drains W(0), x(1); A(0) visible

#pragma unroll
    for (int it = 0; it < 24; ++it) {
        // issue next-step loads FIRST (they complete at the next barrier drain)
        short8 Wn0, Wn1, Wn2;
        float2 Xn2;
        if (it < 23) {
            const short* wn = wt0 + (it + 1) * 512;
            Wn0 = *(const short8*)(wn);
            Wn1 = *(const short8*)(wn + 12288);
            Wn2 = *(const short8*)(wn + 24576);
        }
        if (it < 22) Xn2 = *(const float2*)(xp + (it + 2) * 32);

        // compute step it
        short8 a = *(const short8*)((const short*)Abuf[it % 3] + l16 * 32 + quad * 8);
        acc[0] = __builtin_amdgcn_mfma_f32_16x16x32_bf16(a, Wc0, acc[0], 0, 0, 0);
        acc[1] = __builtin_amdgcn_mfma_f32_16x16x32_bf16(a, Wc1, acc[1], 0, 0, 0);
        acc[2] = __builtin_amdgcn_mfma_f32_16x16x32_bf16(a, Wc2, acc[2], 0, 0, 0);

        // prepare A(it+1) from Xn (completed at the last barrier)
        if (it < 23)
            Abuf[(it + 1) % 3][aidx] = ((unsigned short)f2bf(Xn.x)) | ((unsigned)f2bf(Xn.y) << 16);
        Xn = Xn2;
        Wc0 = Wn0; Wc1 = Wn1; Wc2 = Wn2;
        __syncthreads();
    }

    // epilogue: each wave writes its own 3 output tiles
#pragma unroll
    for (int t = 0; t < 3; ++t) {
        const int p = p0 + t, j = p >> 2, nt = p & 3;
        if (j < 2) {        // Q, K row-major  (C layout: col=l16, row=quad*4+r)
            short* dst = (j == 0) ? Qs : Kb;
#pragma unroll
            for (int r = 0; r < 4; ++r)
                dst[(size_t)(m0 + quad * 4 + r) * 64 + nt * 16 + l16] = f2bf(acc[t][r]);
        } else {            // V: stage for transpose
#pragma unroll
            for (int r = 0; r < 4; ++r)
                sm[(quad * 4 + r) * 72 + nt * 16 + l16] = f2bf(acc[t][r]);
        }
    }
    __syncthreads();
    {   // all 256 threads: V -> Vtr[b][h][s'], s' = sigma^-1(s) within 64-blocks:
        // s bits [5]=ks [4]=hi [3:2]=qd [1:0]=lo  ->  s' bits [5]=ks [4:3]=qd [2]=hi [1:0]=lo
        const int h = tid >> 2, si = (tid & 3) * 4;
        const int b = m0 >> 12, s0 = m0 & 4095;
        const int sb = s0 + si;                      // 4-aligned source s
        const int jb = (sb & ~63) | (sb & 0x23) | ((sb & 0x0C) << 1) | ((sb & 0x10) >> 2);
        short4v tmp;
#pragma unroll
        for (int i = 0; i < 4; ++i) tmp[i] = sm[(si + i) * 72 + h];
        *(short4v*)(Vtr + (size_t)(b * 64 + h) * 4096 + jb) = tmp;
    }
}

// ---------------- kernel 2: flash attention, register-direct (v5) -----------
// Zero LDS, zero barriers. Each wave owns 64 q-rows and streams K/V tiles
// straight from L2 into MFMA fragments (the LDS staging was a pass-through
// copy: frag read patterns are 16 rows x 64B fully-consumed segments in
// global too). Pipelining by register-slot recycling: K(t+1) loads issued
// into the just-consumed K regs right after QK(t); V(t+1) after PV(t) --
// each gets ~500 cyc of compute cover, zero extra VGPR. 2 blocks/CU.
__global__ __launch_bounds__(256, 2) void attn_kernel(
    const short* __restrict__ Qs, const short* __restrict__ Kb, const short* __restrict__ Vt,
    float* __restrict__ Opart, float* __restrict__ Ll, int kv_len)
{
    const int tid = threadIdx.x;
    const int wave = tid >> 6, lane = tid & 63, quad = lane >> 4, l16 = lane & 15;
    const int qt = blockIdx.x, b = blockIdx.y, sp = blockIdx.z;
    const int q0 = qt * 256;
    const int bS = b * 4096;
    const int kv0 = sp * kv_len;

    // Q as B-fragments: lane holds Q[q = ntq*16 + l16][h = ks*32 + quad*8 + i]
    short8 qb[4][2];
#pragma unroll
    for (int ntq = 0; ntq < 4; ++ntq)
#pragma unroll
        for (int ks = 0; ks < 2; ++ks)
            qb[ntq][ks] = *(const short8*)(Qs + (size_t)(bS + q0 + wave * 64 + ntq * 16 + l16) * 64 + ks * 32 + quad * 8);

    float4v o[4][4];
#pragma unroll
    for (int ntq = 0; ntq < 4; ++ntq)
#pragma unroll
        for (int nt = 0; nt < 4; ++nt) o[ntq][nt] = (float4v){0.f, 0.f, 0.f, 0.f};
    float rs[4] = {0.f, 0.f, 0.f, 0.f};

    // per-lane fragment base pointers (same addresses the LDS copies held)
    const short* kp = Kb + (size_t)(bS + kv0 + l16) * 64 + quad * 8;       // +mtk*1024 (+32 for ks=1), tile +4096
    const short* vp = Vt + (size_t)(b * 64 + l16) * 4096 + kv0 + quad * 8; // +nt*65536 (+32 for ks=1), tile +64

    const int ntiles = kv_len >> 6;

    // prologue: K(0), V(0) into fragment registers
    short8 ka[4], kc[4], va[4], vb[4];
#pragma unroll
    for (int mtk = 0; mtk < 4; ++mtk) {
        ka[mtk] = *(const short8*)(kp + mtk * 1024);
        kc[mtk] = *(const short8*)(kp + mtk * 1024 + 32);
    }
#pragma unroll
    for (int nt = 0; nt < 4; ++nt) {
        va[nt] = *(const short8*)(vp + (size_t)nt * 65536);
        vb[nt] = *(const short8*)(vp + (size_t)nt * 65536 + 32);
    }

    for (int t = 0; t < ntiles; ++t) {
        // S^T = K Q^T; lane holds S[q=l16 (+16*ntq)][kv=mtk*16+quad*4+r].
        // exp2 results packed straight into PV A-frag dwords (sigma layout).
        union { unsigned u[8]; short8 h[2]; } pa0, pa1, pa2, pa3;
#pragma unroll
        for (int mtk = 0; mtk < 4; ++mtk) {
            short8 k0 = ka[mtk];
            short8 k1 = kc[mtk];
#define QK_NTQ(PA, NTQ)                                                          \
            {                                                                    \
                float4v s = (float4v){0.f, 0.f, 0.f, 0.f};                       \
                __builtin_amdgcn_s_setprio(1);                                   \
                s = __builtin_amdgcn_mfma_f32_16x16x32_bf16(k0, qb[NTQ][0], s, 0, 0, 0); \
                s = __builtin_amdgcn_mfma_f32_16x16x32_bf16(k1, qb[NTQ][1], s, 0, 0, 0); \
                __builtin_amdgcn_s_setprio(0);                                   \
                float e0 = fast_exp2(s[0]), e1 = fast_exp2(s[1]);                \
                float e2 = fast_exp2(s[2]), e3 = fast_exp2(s[3]);                \
                rs[NTQ] += (e0 + e1) + (e2 + e3);                                \
                PA.u[mtk * 2]     = cvt_pk_bf16(e0, e1);                         \
                PA.u[mtk * 2 + 1] = cvt_pk_bf16(e2, e3);                         \
            }
            QK_NTQ(pa0, 0)
            QK_NTQ(pa1, 1)
            QK_NTQ(pa2, 2)
            QK_NTQ(pa3, 3)
#undef QK_NTQ
        }

        // K regs consumed -> issue K(t+1) into them now; PV below covers latency
        if (t + 1 < ntiles) {
            const short* kn = kp + (size_t)(t + 1) * 4096;
#pragma unroll
            for (int mtk = 0; mtk < 4; ++mtk) {
                ka[mtk] = *(const short8*)(kn + mtk * 1024);
                kc[mtk] = *(const short8*)(kn + mtk * 1024 + 32);
            }
        }

        // O += P V   (A-frag = lane-local packed P, B-frag = sigma-ordered V)
#pragma unroll
        for (int ks = 0; ks < 2; ++ks) {
            __builtin_amdgcn_s_setprio(1);
#pragma unroll
            for (int nt = 0; nt < 4; ++nt) {
                short8 bf = (ks == 0) ? va[nt] : vb[nt];
                o[0][nt] = __builtin_amdgcn_mfma_f32_16x16x32_bf16(pa0.h[ks], bf, o[0][nt], 0, 0, 0);
                o[1][nt] = __builtin_amdgcn_mfma_f32_16x16x32_bf16(pa1.h[ks], bf, o[1][nt], 0, 0, 0);
                o[2][nt] = __builtin_amdgcn_mfma_f32_16x16x32_bf16(pa2.h[ks], bf, o[2][nt], 0, 0, 0);
                o[3][nt] = __builtin_amdgcn_mfma_f32_16x16x32_bf16(pa3.h[ks], bf, o[3][nt], 0, 0, 0);
            }
            __builtin_amdgcn_s_setprio(0);
        }

        // V regs consumed -> issue V(t+1); next tile's QK+exp covers latency
        if (t + 1 < ntiles) {
            const short* vn = vp + (t + 1) * 64;
#pragma unroll
            for (int nt = 0; nt < 4; ++nt) {
                va[nt] = *(const short8*)(vn + (size_t)nt * 65536);
                vb[nt] = *(const short8*)(vn + (size_t)nt * 65536 + 32);
            }
        }
    }

    // row-sums: lane partial covers its 4 quads' kv rows -> reduce over quads only
#pragma unroll
    for (int ntq = 0; ntq < 4; ++ntq) {
        rs[ntq] += __shfl_xor(rs[ntq], 16);
        rs[ntq] += __shfl_xor(rs[ntq], 32);
    }

#pragma unroll
    for (int ntq = 0; ntq < 4; ++ntq) {
#pragma unroll
        for (int nt = 0; nt < 4; ++nt)
#pragma unroll
            for (int r = 0; r < 4; ++r) {
                int qrow = q0 + wave * 64 + ntq * 16 + quad * 4 + r;
                Opart[((size_t)sp * 16384 + bS + qrow) * 64 + nt * 16 + l16] = o[ntq][nt][r];
            }
        if (quad == 0)
            Ll[(size_t)sp * 16384 + bS + q0 + wave * 64 + ntq * 16 + l16] = rs[ntq];
    }
}

// ---------------- kernel 3: combine kv-split partials (no exp needed) --------
__global__ void combine_kernel(const float* __restrict__ Opart, const float* __restrict__ Ll,
                               float* __restrict__ out, int nsplit) {
    int idx = blockIdx.x * 256 + threadIdx.x;   // 1048576 outputs
    int q = idx >> 6;
    float den = 0.f, num = 0.f;
    for (int s = 0; s < nsplit; ++s) {
        den += Ll[s * 16384 + q];
        num += Opart[(size_t)s * 1048576 + idx];
    }
    out[idx] = num / den;
}

extern "C" void kernel_launch(void* const* d_in, const int* in_sizes, int n_in,
                              void* d_out, int out_size, void* d_ws, size_t ws_size,
                              hipStream_t stream) {
    const float* x  = (const float*)d_in[0];
    const float* Wk = (const float*)d_in[1];
    const float* Wq = (const float*)d_in[2];
    const float* Wv = (const float*)d_in[3];
    float* out = (float*)d_out;

    char* w = (char*)d_ws;
    size_t off = 0;
    auto take = [&](size_t bytes) -> void* {
        void* p = w + off;
        off = (off + bytes + 255) & ~(size_t)255;
        return p;
    };
    short* Qs  = (short*)take((size_t)16384 * 64 * 2);
    short* Kb  = (short*)take((size_t)16384 * 64 * 2);
    short* Vt  = (short*)take((size_t)16384 * 64 * 2);
    short* Wt3 = (short*)take((size_t)3 * 64 * 768 * 2);

    size_t base = off;
    int nsplit = 8;         // QBLK=256 -> grid (16,4,8) = 512 blocks = 2/CU
    while (nsplit > 1) {
        size_t need = base + (((size_t)nsplit * 16384 * 4 + 255) & ~(size_t)255)
                      + (size_t)nsplit * 16384 * 64 * 4 + 512;
        if (need <= ws_size) break;
        nsplit >>= 1;
    }
    float* Ll    = (float*)take((size_t)nsplit * 16384 * 4);
    float* Opart = (float*)take((size_t)nsplit * 16384 * 64 * 4);

    wtrans_kernel<<<576, 256, 0, stream>>>(Wk, Wq, Wv, Wt3);
    proj_kernel<<<1024, 256, 0, stream>>>(x, Wt3, Qs, Kb, Vt);
    dim3 ag(16, 4, nsplit);
    attn_kernel<<<ag, 256, 0, stream>>>(Qs, Kb, Vt, Opart, Ll, 4096 / nsplit);
    combine_kernel<<<4096, 256, 0, stream>>>(Opart, Ll, out, nsplit);
}

// Round 5
// 159.411 us; speedup vs baseline: 1.0821x; 1.0821x over previous
//
#include <hip/hip_runtime.h>

typedef __attribute__((ext_vector_type(8))) short short8;
typedef __attribute__((ext_vector_type(4))) short short4v;
typedef __attribute__((ext_vector_type(4))) float float4v;

__device__ __forceinline__ short f2bf(float f) {
    union { float f; unsigned u; } v; v.f = f;
    return (short)((v.u + 0x7fffu + ((v.u >> 16) & 1u)) >> 16);
}

__device__ __forceinline__ float fast_exp2(float x) {
#if __has_builtin(__builtin_amdgcn_exp2f)
    return __builtin_amdgcn_exp2f(x);
#else
    return exp2f(x);
#endif
}

// pack two f32 -> one dword of 2 bf16 (low = lo, high = hi); no builtin on gfx950
__device__ __forceinline__ unsigned cvt_pk_bf16(float lo, float hi) {
    unsigned r;
    asm("v_cvt_pk_bf16_f32 %0, %1, %2" : "=v"(r) : "v"(lo), "v"(hi));
    return r;
}

// ---------------- kernel 0: weight transpose+convert (b-frag tiled) ---------
// Wt3T layout: 12 tiles p=j*4+nt (j: 0=Q,1=K,2=V; nt: n-16-tile), each tile
// [24 ksteps][64 lanes][8 shorts]: lane (l16,quad) slot i holds
// W_j[k=kstep*32+quad*8+i][n=nt*16+l16].  A wave's b-frag load is 1 KB contig.
__global__ void wtrans_kernel(const float* __restrict__ Wk, const float* __restrict__ Wq,
                              const float* __restrict__ Wv, short* __restrict__ Wt3T) {
    int idx = blockIdx.x * 256 + threadIdx.x;       // 3*64*768 = 147456
    int p = idx / 12288;                            // 12 tiles of 24*512
    int rem = idx - p * 12288;
    int kstep = rem / 512;
    int r2 = rem - kstep * 512;
    int lane = r2 >> 3, i = r2 & 7;
    int quad = lane >> 4, l16 = lane & 15;
    int j = p >> 2, nt = p & 3;
    int n = nt * 16 + l16;
    int k = kstep * 32 + quad * 8 + i;
    const float* W = (j == 0) ? Wq : (j == 1 ? Wk : Wv);
    // log2(e)/sqrt(768) folded into Wq -> scores arrive in log2 domain
    float scale = (j == 0) ? 0.05205877f : 1.0f;
    Wt3T[idx] = f2bf(W[k * 64 + n] * scale);
}

// ---------------- kernel 1: QKV projection, N-split, shared-A LDS -----------
// 1024 blocks x 16 rows. x tile staged+converted ONCE per block into LDS
// (A-layout, 3-slot rotation, one barrier/k-step). Wave w owns output tiles
// p=3w..3w+2; W-frags and x loads issued right after the barrier so the next
// barrier's vmcnt(0) drain completes them -> latency absorbed by the barrier.
// V is written to Vtr with the sigma column permutation (within 64-aligned
// s-blocks) so the attention kernel's PV A-fragments become lane-local.
__global__ __launch_bounds__(256, 4) void proj_kernel(
    const float* __restrict__ x, const short* __restrict__ Wt3T,
    short* __restrict__ Qs, short* __restrict__ Kb, short* __restrict__ Vtr)
{
    __shared__ alignas(16) int Abuf[3][256];        // 3 slots of [16 rows][32 k] bf16
    __shared__ alignas(16) short sm[16 * 72];       // V transpose staging
    const int tid = threadIdx.x;
    const int wave = tid >> 6, lane = tid & 63, quad = lane >> 4, l16 = lane & 15;
    const int m0 = blockIdx.x * 16;
    const int p0 = wave * 3;

    // x cooperative staging: thread -> 2 fp32 at (row = tid>>4, col = (tid&15)*2)
    const int xrow = tid >> 4, xcol = (tid & 15) * 2;
    const float* xp = x + (size_t)(m0 + xrow) * 768 + xcol;
    const int aidx = xrow * 16 + (tid & 15);
    // W: wave-private b-frag stream, tile t at (p0+t)*24*512, step at it*512
    const short* wt0 = Wt3T + (size_t)(p0 * 24) * 512 + lane * 8;

    float4v acc[3];
#pragma unroll
    for (int t = 0; t < 3; ++t) acc[t] = (float4v){0.f, 0.f, 0.f, 0.f};

    // prologue: A(0) direct, issue W(0), x(1)
    {
        float2 u = *(const float2*)xp;
        Abuf[0][aidx] = ((unsigned short)f2bf(u.x)) | ((unsigned)f2bf(u.y) << 16);
    }
    short8 Wc0 = *(const short8*)(wt0);
    short8 Wc1 = *(const short8*)(wt0 + 12288);
    short8 Wc2 = *(const short8*)(wt0 + 24576);
    float2 Xn = *(const float2*)(xp + 32);
    __syncthreads();        // drains W(0), x(1); A(0) visible

#pragma unroll
    for (int it = 0; it < 24; ++it) {
        // issue next-step loads FIRST (they complete at the next barrier drain)
        short8 Wn0, Wn1, Wn2;
        float2 Xn2;
        if (it < 23) {
            const short* wn = wt0 + (it + 1) * 512;
            Wn0 = *(const short8*)(wn);
            Wn1 = *(const short8*)(wn + 12288);
            Wn2 = *(const short8*)(wn + 24576);
        }
        if (it < 22) Xn2 = *(const float2*)(xp + (it + 2) * 32);

        // compute step it
        short8 a = *(const short8*)((const short*)Abuf[it % 3] + l16 * 32 + quad * 8);
        acc[0] = __builtin_amdgcn_mfma_f32_16x16x32_bf16(a, Wc0, acc[0], 0, 0, 0);
        acc[1] = __builtin_amdgcn_mfma_f32_16x16x32_bf16(a, Wc1, acc[1], 0, 0, 0);
        acc[2] = __builtin_amdgcn_mfma_f32_16x16x32_bf16(a, Wc2, acc[2], 0, 0, 0);

        // prepare A(it+1) from Xn (completed at the last barrier)
        if (it < 23)
            Abuf[(it + 1) % 3][aidx] = ((unsigned short)f2bf(Xn.x)) | ((unsigned)f2bf(Xn.y) << 16);
        Xn = Xn2;
        Wc0 = Wn0; Wc1 = Wn1; Wc2 = Wn2;
        __syncthreads();
    }

    // epilogue: each wave writes its own 3 output tiles
#pragma unroll
    for (int t = 0; t < 3; ++t) {
        const int p = p0 + t, j = p >> 2, nt = p & 3;
        if (j < 2) {        // Q, K row-major  (C layout: col=l16, row=quad*4+r)
            short* dst = (j == 0) ? Qs : Kb;
#pragma unroll
            for (int r = 0; r < 4; ++r)
                dst[(size_t)(m0 + quad * 4 + r) * 64 + nt * 16 + l16] = f2bf(acc[t][r]);
        } else {            // V: stage for transpose
#pragma unroll
            for (int r = 0; r < 4; ++r)
                sm[(quad * 4 + r) * 72 + nt * 16 + l16] = f2bf(acc[t][r]);
        }
    }
    __syncthreads();
    {   // all 256 threads: V -> Vtr[b][h][s'], s' = sigma^-1(s) within 64-blocks:
        // s bits [5]=ks [4]=hi [3:2]=qd [1:0]=lo  ->  s' bits [5]=ks [4:3]=qd [2]=hi [1:0]=lo
        const int h = tid >> 2, si = (tid & 3) * 4;
        const int b = m0 >> 12, s0 = m0 & 4095;
        const int sb = s0 + si;                      // 4-aligned source s
        const int jb = (sb & ~63) | (sb & 0x23) | ((sb & 0x0C) << 1) | ((sb & 0x10) >> 2);
        short4v tmp;
#pragma unroll
        for (int i = 0; i < 4; ++i) tmp[i] = sm[(si + i) * 72 + h];
        *(short4v*)(Vtr + (size_t)(b * 64 + h) * 4096 + jb) = tmp;
    }
}

// ---------------- kernel 2: flash attention (v6) -----------------------------
// Recombination of the proven pieces: QBLK=128 LDS staging shared by 4 waves
// (R2-proven), sigma-PV lane-local P (R2), double-buffered LDS with ONE
// barrier per tile + t+2 register prefetch (R3's pipeline), at 4 blocks/CU
// (nsplit=8 -> 1024 blocks, LDS 36.9 KB, launch_bounds(256,4)): 16 waves/CU
// hide the per-tile barrier drain that R3's 1 block/CU exposed.
__global__ __launch_bounds__(256, 4) void attn_kernel(
    const short* __restrict__ Qs, const short* __restrict__ Kb, const short* __restrict__ Vt,
    float* __restrict__ Opart, float* __restrict__ Ll, int kv_len)
{
    __shared__ alignas(16) short Kl[2][64 * 72];    // [buf][kv 64][h 64+8]
    __shared__ alignas(16) short Vl[2][64 * 72];    // [buf][h 64][kv' 64+8] (sigma)

    const int tid = threadIdx.x;
    const int wave = tid >> 6, lane = tid & 63, quad = lane >> 4, l16 = lane & 15;
    const int qt = blockIdx.x, b = blockIdx.y, sp = blockIdx.z;
    const int q0 = qt * 128;
    const int bS = b * 4096;
    const int kv0 = sp * kv_len;

    // Q as B-fragments: lane holds Q[q = ntq*16 + l16][h = ks*32 + quad*8 + i]
    short8 qb[2][2];
#pragma unroll
    for (int ntq = 0; ntq < 2; ++ntq)
#pragma unroll
        for (int ks = 0; ks < 2; ++ks)
            qb[ntq][ks] = *(const short8*)(Qs + (size_t)(bS + q0 + wave * 32 + ntq * 16 + l16) * 64 + ks * 32 + quad * 8);

    float4v o[2][4];
#pragma unroll
    for (int ntq = 0; ntq < 2; ++ntq)
#pragma unroll
        for (int nt = 0; nt < 4; ++nt) o[ntq][nt] = (float4v){0.f, 0.f, 0.f, 0.f};
    float rs[2] = {0.f, 0.f};

    const int sr = tid >> 2, sc = (tid & 3) * 16;

    const short* ksrc0 = Kb + (size_t)(bS + kv0 + sr) * 64 + sc;
    const short* vsrc0 = Vt + (size_t)(b * 64 + sr) * 4096 + kv0 + sc;

    const int ntiles = kv_len >> 6;

    // prologue: tile0 -> regs -> LDS buf0; issue tile1 loads; one barrier
    short8 kr0 = *(const short8*)ksrc0;
    short8 kr1 = *(const short8*)(ksrc0 + 8);
    short8 vr0 = *(const short8*)vsrc0;
    short8 vr1 = *(const short8*)(vsrc0 + 8);
    *(short8*)&Kl[0][sr * 72 + sc]     = kr0;
    *(short8*)&Kl[0][sr * 72 + sc + 8] = kr1;
    *(short8*)&Vl[0][sr * 72 + sc]     = vr0;
    *(short8*)&Vl[0][sr * 72 + sc + 8] = vr1;
    if (ntiles > 1) {
        const short* kn = ksrc0 + (size_t)4096;
        kr0 = *(const short8*)kn;
        kr1 = *(const short8*)(kn + 8);
        const short* vn = vsrc0 + 64;
        vr0 = *(const short8*)vn;
        vr1 = *(const short8*)(vn + 8);
    }
    __syncthreads();

    for (int t = 0; t < ntiles; ++t) {
        const int c = t & 1;
        const short* klc = &Kl[c][0];
        const short* vlc = &Vl[c][0];

        // S^T = K Q^T; lane holds S[q=l16 (+16*ntq)][kv=mtk*16+quad*4+r].
        // exp2 results packed straight into PV A-frag dwords (sigma layout).
        union { unsigned u[8]; short8 h[2]; } pa0, pa1;
#pragma unroll
        for (int mtk = 0; mtk < 4; ++mtk) {
            short8 k0 = *(const short8*)&klc[(mtk * 16 + l16) * 72 + quad * 8];
            short8 k1 = *(const short8*)&klc[(mtk * 16 + l16) * 72 + 32 + quad * 8];
#define QK_NTQ(PA, NTQ)                                                          \
            {                                                                    \
                float4v s = (float4v){0.f, 0.f, 0.f, 0.f};                       \
                __builtin_amdgcn_s_setprio(1);                                   \
                s = __builtin_amdgcn_mfma_f32_16x16x32_bf16(k0, qb[NTQ][0], s, 0, 0, 0); \
                s = __builtin_amdgcn_mfma_f32_16x16x32_bf16(k1, qb[NTQ][1], s, 0, 0, 0); \
                __builtin_amdgcn_s_setprio(0);                                   \
                float e0 = fast_exp2(s[0]), e1 = fast_exp2(s[1]);                \
                float e2 = fast_exp2(s[2]), e3 = fast_exp2(s[3]);                \
                rs[NTQ] += (e0 + e1) + (e2 + e3);                                \
                PA.u[mtk * 2]     = cvt_pk_bf16(e0, e1);                         \
                PA.u[mtk * 2 + 1] = cvt_pk_bf16(e2, e3);                         \
            }
            QK_NTQ(pa0, 0)
            QK_NTQ(pa1, 1)
#undef QK_NTQ
        }

        // O += P V   (A-frag = lane-local packed P, B-frag = sigma-ordered V)
#pragma unroll
        for (int ks = 0; ks < 2; ++ks) {
            short8 bf[4];
#pragma unroll
            for (int nt = 0; nt < 4; ++nt)
                bf[nt] = *(const short8*)&vlc[(nt * 16 + l16) * 72 + ks * 32 + quad * 8];
            __builtin_amdgcn_s_setprio(1);
#pragma unroll
            for (int nt = 0; nt < 4; ++nt)
                o[0][nt] = __builtin_amdgcn_mfma_f32_16x16x32_bf16(pa0.h[ks], bf[nt], o[0][nt], 0, 0, 0);
#pragma unroll
            for (int nt = 0; nt < 4; ++nt)
                o[1][nt] = __builtin_amdgcn_mfma_f32_16x16x32_bf16(pa1.h[ks], bf[nt], o[1][nt], 0, 0, 0);
            __builtin_amdgcn_s_setprio(0);
        }

        // stage tile t+1 into the other buffer (no hazard: all reads above
        // used buf c; the previous barrier cleared last tile's readers of c^1)
        if (t + 1 < ntiles) {
            short* kd = &Kl[c ^ 1][0];
            short* vd = &Vl[c ^ 1][0];
            *(short8*)&kd[sr * 72 + sc]     = kr0;
            *(short8*)&kd[sr * 72 + sc + 8] = kr1;
            *(short8*)&vd[sr * 72 + sc]     = vr0;
            *(short8*)&vd[sr * 72 + sc + 8] = vr1;
        }
        // issue tile t+2 global loads; they land during tile t+1's compute
        if (t + 2 < ntiles) {
            const short* kn = ksrc0 + (size_t)(t + 2) * 4096;
            kr0 = *(const short8*)kn;
            kr1 = *(const short8*)(kn + 8);
            const short* vn = vsrc0 + (t + 2) * 64;
            vr0 = *(const short8*)vn;
            vr1 = *(const short8*)(vn + 8);
        }
        __syncthreads();    // single barrier per tile (double-buffered LDS)
    }

    // row-sums: lane partial covers its 4 quads' kv rows -> reduce over quads only
#pragma unroll
    for (int ntq = 0; ntq < 2; ++ntq) {
        rs[ntq] += __shfl_xor(rs[ntq], 16);
        rs[ntq] += __shfl_xor(rs[ntq], 32);
    }

#pragma unroll
    for (int ntq = 0; ntq < 2; ++ntq) {
#pragma unroll
        for (int nt = 0; nt < 4; ++nt)
#pragma unroll
            for (int r = 0; r < 4; ++r) {
                int qrow = q0 + wave * 32 + ntq * 16 + quad * 4 + r;
                Opart[((size_t)sp * 16384 + bS + qrow) * 64 + nt * 16 + l16] = o[ntq][nt][r];
            }
        if (quad == 0)
            Ll[(size_t)sp * 16384 + bS + q0 + wave * 32 + ntq * 16 + l16] = rs[ntq];
    }
}

// ---------------- kernel 3: combine kv-split partials (no exp needed) --------
__global__ void combine_kernel(const float* __restrict__ Opart, const float* __restrict__ Ll,
                               float* __restrict__ out, int nsplit) {
    int idx = blockIdx.x * 256 + threadIdx.x;   // 1048576 outputs
    int q = idx >> 6;
    float den = 0.f, num = 0.f;
    for (int s = 0; s < nsplit; ++s) {
        den += Ll[s * 16384 + q];
        num += Opart[(size_t)s * 1048576 + idx];
    }
    out[idx] = num / den;
}

extern "C" void kernel_launch(void* const* d_in, const int* in_sizes, int n_in,
                              void* d_out, int out_size, void* d_ws, size_t ws_size,
                              hipStream_t stream) {
    const float* x  = (const float*)d_in[0];
    const float* Wk = (const float*)d_in[1];
    const float* Wq = (const float*)d_in[2];
    const float* Wv = (const float*)d_in[3];
    float* out = (float*)d_out;

    char* w = (char*)d_ws;
    size_t off = 0;
    auto take = [&](size_t bytes) -> void* {
        void* p = w + off;
        off = (off + bytes + 255) & ~(size_t)255;
        return p;
    };
    short* Qs  = (short*)take((size_t)16384 * 64 * 2);
    short* Kb  = (short*)take((size_t)16384 * 64 * 2);
    short* Vt  = (short*)take((size_t)16384 * 64 * 2);
    short* Wt3 = (short*)take((size_t)3 * 64 * 768 * 2);

    size_t base = off;
    int nsplit = 8;         // QBLK=128 -> grid (32,4,8) = 1024 blocks = 4/CU
    while (nsplit > 1) {
        size_t need = base + (((size_t)nsplit * 16384 * 4 + 255) & ~(size_t)255)
                      + (size_t)nsplit * 16384 * 64 * 4 + 512;
        if (need <= ws_size) break;
        nsplit >>= 1;
    }
    float* Ll    = (float*)take((size_t)nsplit * 16384 * 4);
    float* Opart = (float*)take((size_t)nsplit * 16384 * 64 * 4);

    wtrans_kernel<<<576, 256, 0, stream>>>(Wk, Wq, Wv, Wt3);
    proj_kernel<<<1024, 256, 0, stream>>>(x, Wt3, Qs, Kb, Vt);
    dim3 ag(32, 4, nsplit);
    attn_kernel<<<ag, 256, 0, stream>>>(Qs, Kb, Vt, Opart, Ll, 4096 / nsplit);
    combine_kernel<<<4096, 256, 0, stream>>>(Opart, Ll, out, nsplit);
}

// Round 6
// 135.581 us; speedup vs baseline: 1.2723x; 1.1758x over previous
//
#include <hip/hip_runtime.h>

typedef __attribute__((ext_vector_type(8))) short short8;
typedef __attribute__((ext_vector_type(4))) short short4v;
typedef __attribute__((ext_vector_type(4))) float float4v;

__device__ __forceinline__ short f2bf(float f) {
    union { float f; unsigned u; } v; v.f = f;
    return (short)((v.u + 0x7fffu + ((v.u >> 16) & 1u)) >> 16);
}

__device__ __forceinline__ float fast_exp2(float x) {
#if __has_builtin(__builtin_amdgcn_exp2f)
    return __builtin_amdgcn_exp2f(x);
#else
    return exp2f(x);
#endif
}

// pack two f32 -> one dword of 2 bf16 (low = lo, high = hi); no builtin on gfx950
__device__ __forceinline__ unsigned cvt_pk_bf16(float lo, float hi) {
    unsigned r;
    asm("v_cvt_pk_bf16_f32 %0, %1, %2" : "=v"(r) : "v"(lo), "v"(hi));
    return r;
}

// ---------------- kernel 0: weight transpose+convert (b-frag tiled) ---------
// Wt3T layout: 12 tiles p=j*4+nt (j: 0=Q,1=K,2=V; nt: n-16-tile), each tile
// [24 ksteps][64 lanes][8 shorts]: lane (l16,quad) slot i holds
// W_j[k=kstep*32+quad*8+i][n=nt*16+l16].  A wave's b-frag load is 1 KB contig.
__global__ void wtrans_kernel(const float* __restrict__ Wk, const float* __restrict__ Wq,
                              const float* __restrict__ Wv, short* __restrict__ Wt3T) {
    int idx = blockIdx.x * 256 + threadIdx.x;       // 3*64*768 = 147456
    int p = idx / 12288;                            // 12 tiles of 24*512
    int rem = idx - p * 12288;
    int kstep = rem / 512;
    int r2 = rem - kstep * 512;
    int lane = r2 >> 3, i = r2 & 7;
    int quad = lane >> 4, l16 = lane & 15;
    int j = p >> 2, nt = p & 3;
    int n = nt * 16 + l16;
    int k = kstep * 32 + quad * 8 + i;
    const float* W = (j == 0) ? Wq : (j == 1 ? Wk : Wv);
    // log2(e)/sqrt(768) folded into Wq -> scores arrive in log2 domain
    float scale = (j == 0) ? 0.05205877f : 1.0f;
    Wt3T[idx] = f2bf(W[k * 64 + n] * scale);
}

// ---------------- kernel 1: QKV projection, N-split, shared-A LDS -----------
// 1024 blocks x 16 rows. x tile staged+converted ONCE per block into LDS
// (A-layout, 3-slot rotation, one barrier/k-step). Wave w owns output tiles
// p=3w..3w+2; W-frags and x loads issued right after the barrier so the next
// barrier's vmcnt(0) drain completes them -> latency absorbed by the barrier.
// V is written to Vtr with the sigma column permutation (within 64-aligned
// s-blocks) so the attention kernel's PV A-fragments become lane-local.
__global__ __launch_bounds__(256, 4) void proj_kernel(
    const float* __restrict__ x, const short* __restrict__ Wt3T,
    short* __restrict__ Qs, short* __restrict__ Kb, short* __restrict__ Vtr)
{
    __shared__ alignas(16) int Abuf[3][256];        // 3 slots of [16 rows][32 k] bf16
    __shared__ alignas(16) short sm[16 * 72];       // V transpose staging
    const int tid = threadIdx.x;
    const int wave = tid >> 6, lane = tid & 63, quad = lane >> 4, l16 = lane & 15;
    const int m0 = blockIdx.x * 16;
    const int p0 = wave * 3;

    // x cooperative staging: thread -> 2 fp32 at (row = tid>>4, col = (tid&15)*2)
    const int xrow = tid >> 4, xcol = (tid & 15) * 2;
    const float* xp = x + (size_t)(m0 + xrow) * 768 + xcol;
    const int aidx = xrow * 16 + (tid & 15);
    // W: wave-private b-frag stream, tile t at (p0+t)*24*512, step at it*512
    const short* wt0 = Wt3T + (size_t)(p0 * 24) * 512 + lane * 8;

    float4v acc[3];
#pragma unroll
    for (int t = 0; t < 3; ++t) acc[t] = (float4v){0.f, 0.f, 0.f, 0.f};

    // prologue: A(0) direct, issue W(0), x(1)
    {
        float2 u = *(const float2*)xp;
        Abuf[0][aidx] = ((unsigned short)f2bf(u.x)) | ((unsigned)f2bf(u.y) << 16);
    }
    short8 Wc0 = *(const short8*)(wt0);
    short8 Wc1 = *(const short8*)(wt0 + 12288);
    short8 Wc2 = *(const short8*)(wt0 + 24576);
    float2 Xn = *(const float2*)(xp + 32);
    __syncthreads();        // drains W(0), x(1); A(0) visible

#pragma unroll
    for (int it = 0; it < 24; ++it) {
        // issue next-step loads FIRST (they complete at the next barrier drain)
        short8 Wn0, Wn1, Wn2;
        float2 Xn2;
        if (it < 23) {
            const short* wn = wt0 + (it + 1) * 512;
            Wn0 = *(const short8*)(wn);
            Wn1 = *(const short8*)(wn + 12288);
            Wn2 = *(const short8*)(wn + 24576);
        }
        if (it < 22) Xn2 = *(const float2*)(xp + (it + 2) * 32);

        // compute step it
        short8 a = *(const short8*)((const short*)Abuf[it % 3] + l16 * 32 + quad * 8);
        acc[0] = __builtin_amdgcn_mfma_f32_16x16x32_bf16(a, Wc0, acc[0], 0, 0, 0);
        acc[1] = __builtin_amdgcn_mfma_f32_16x16x32_bf16(a, Wc1, acc[1], 0, 0, 0);
        acc[2] = __builtin_amdgcn_mfma_f32_16x16x32_bf16(a, Wc2, acc[2], 0, 0, 0);

        // prepare A(it+1) from Xn (completed at the last barrier)
        if (it < 23)
            Abuf[(it + 1) % 3][aidx] = ((unsigned short)f2bf(Xn.x)) | ((unsigned)f2bf(Xn.y) << 16);
        Xn = Xn2;
        Wc0 = Wn0; Wc1 = Wn1; Wc2 = Wn2;
        __syncthreads();
    }

    // epilogue: each wave writes its own 3 output tiles
#pragma unroll
    for (int t = 0; t < 3; ++t) {
        const int p = p0 + t, j = p >> 2, nt = p & 3;
        if (j < 2) {        // Q, K row-major  (C layout: col=l16, row=quad*4+r)
            short* dst = (j == 0) ? Qs : Kb;
#pragma unroll
            for (int r = 0; r < 4; ++r)
                dst[(size_t)(m0 + quad * 4 + r) * 64 + nt * 16 + l16] = f2bf(acc[t][r]);
        } else {            // V: stage for transpose
#pragma unroll
            for (int r = 0; r < 4; ++r)
                sm[(quad * 4 + r) * 72 + nt * 16 + l16] = f2bf(acc[t][r]);
        }
    }
    __syncthreads();
    {   // all 256 threads: V -> Vtr[b][h][s'], s' = sigma^-1(s) within 64-blocks:
        // s bits [5]=ks [4]=hi [3:2]=qd [1:0]=lo  ->  s' bits [5]=ks [4:3]=qd [2]=hi [1:0]=lo
        const int h = tid >> 2, si = (tid & 3) * 4;
        const int b = m0 >> 12, s0 = m0 & 4095;
        const int sb = s0 + si;                      // 4-aligned source s
        const int jb = (sb & ~63) | (sb & 0x23) | ((sb & 0x0C) << 1) | ((sb & 0x10) >> 2);
        short4v tmp;
#pragma unroll
        for (int i = 0; i < 4; ++i) tmp[i] = sm[(si + i) * 72 + h];
        *(short4v*)(Vtr + (size_t)(b * 64 + h) * 4096 + jb) = tmp;
    }
}

// ---------------- kernel 2: flash attention (v7 = R2's proven v3 + occupancy) -
// Identical structure to the 133-us run's attn (single-buffered Kl/Vl, two
// barriers/tile, T14 t+1 prefetch, sigma-PV lane-local P). Changes vs R2:
// nsplit=8 -> grid 1024 blocks (4/CU candidate instead of grid-capped 2/CU),
// launch_bounds(256,3): reg cap ~170 total so the ~120 live regs DON'T spill
// (R5's (256,4) cap of 128 total forced arch VGPRs to 64 -> 100 MB scratch
// traffic, MfmaUtil 12%). Occupancy now set by actual VGPR count, not a cap.
__global__ __launch_bounds__(256, 3) void attn_kernel(
    const short* __restrict__ Qs, const short* __restrict__ Kb, const short* __restrict__ Vt,
    float* __restrict__ Opart, float* __restrict__ Ll, int kv_len)
{
    __shared__ alignas(16) short Kl[64 * 72];       // [kv 64][h 64+8]
    __shared__ alignas(16) short Vl[64 * 72];       // [h 64][kv' 64+8] (sigma order)

    const int tid = threadIdx.x;
    const int wave = tid >> 6, lane = tid & 63, quad = lane >> 4, l16 = lane & 15;
    const int qt = blockIdx.x, b = blockIdx.y, sp = blockIdx.z;
    const int q0 = qt * 128;
    const int bS = b * 4096;
    const int kv0 = sp * kv_len;

    // Q as B-fragments: lane holds Q[q = ntq*16 + l16][h = ks*32 + quad*8 + i]
    short8 qb[2][2];
#pragma unroll
    for (int ntq = 0; ntq < 2; ++ntq)
#pragma unroll
        for (int ks = 0; ks < 2; ++ks)
            qb[ntq][ks] = *(const short8*)(Qs + (size_t)(bS + q0 + wave * 32 + ntq * 16 + l16) * 64 + ks * 32 + quad * 8);

    float4v o[2][4];
#pragma unroll
    for (int ntq = 0; ntq < 2; ++ntq)
#pragma unroll
        for (int nt = 0; nt < 4; ++nt) o[ntq][nt] = (float4v){0.f, 0.f, 0.f, 0.f};
    float rs[2] = {0.f, 0.f};

    const int sr = tid >> 2, sc = (tid & 3) * 16;

    const short* ksrc0 = Kb + (size_t)(bS + kv0 + sr) * 64 + sc;
    const short* vsrc0 = Vt + (size_t)(b * 64 + sr) * 4096 + kv0 + sc;

    // prologue: load tile 0 into registers
    short8 kr0 = *(const short8*)ksrc0;
    short8 kr1 = *(const short8*)(ksrc0 + 8);
    short8 vr0 = *(const short8*)vsrc0;
    short8 vr1 = *(const short8*)(vsrc0 + 8);

    const int ntiles = kv_len >> 6;
    for (int t = 0; t < ntiles; ++t) {
        __syncthreads();                            // all waves done reading prev tile
        *(short8*)&Kl[sr * 72 + sc]     = kr0;      // regs -> LDS (tile t)
        *(short8*)&Kl[sr * 72 + sc + 8] = kr1;
        *(short8*)&Vl[sr * 72 + sc]     = vr0;
        *(short8*)&Vl[sr * 72 + sc + 8] = vr1;
        __syncthreads();                            // LDS tile t visible

        // issue NEXT tile's loads now; compute covers their latency,
        // next iteration's first barrier drains them.
        if (t + 1 < ntiles) {
            const short* kn = ksrc0 + (size_t)(t + 1) * 4096;   // +64 rows
            kr0 = *(const short8*)kn;
            kr1 = *(const short8*)(kn + 8);
            const short* vn = vsrc0 + (t + 1) * 64;             // +64 cols (sigma order)
            vr0 = *(const short8*)vn;
            vr1 = *(const short8*)(vn + 8);
        }

        // S^T = K Q^T; lane holds S[q=l16(+16ntq)][kv=mtk*16+quad*4+r].
        // Pack exp2 results straight into PV A-frag dwords (sigma makes this legal).
        union { unsigned u[8]; short8 h[2]; } pa0, pa1;
#pragma unroll
        for (int mtk = 0; mtk < 4; ++mtk) {
            short8 k0 = *(const short8*)&Kl[(mtk * 16 + l16) * 72 + quad * 8];
            short8 k1 = *(const short8*)&Kl[(mtk * 16 + l16) * 72 + 32 + quad * 8];
            float4v s0 = (float4v){0.f, 0.f, 0.f, 0.f};
            float4v s1 = (float4v){0.f, 0.f, 0.f, 0.f};
            __builtin_amdgcn_s_setprio(1);
            s0 = __builtin_amdgcn_mfma_f32_16x16x32_bf16(k0, qb[0][0], s0, 0, 0, 0);
            s0 = __builtin_amdgcn_mfma_f32_16x16x32_bf16(k1, qb[0][1], s0, 0, 0, 0);
            s1 = __builtin_amdgcn_mfma_f32_16x16x32_bf16(k0, qb[1][0], s1, 0, 0, 0);
            s1 = __builtin_amdgcn_mfma_f32_16x16x32_bf16(k1, qb[1][1], s1, 0, 0, 0);
            __builtin_amdgcn_s_setprio(0);

            float p00 = fast_exp2(s0[0]), p01 = fast_exp2(s0[1]);
            float p02 = fast_exp2(s0[2]), p03 = fast_exp2(s0[3]);
            float p10 = fast_exp2(s1[0]), p11 = fast_exp2(s1[1]);
            float p12 = fast_exp2(s1[2]), p13 = fast_exp2(s1[3]);
            rs[0] += (p00 + p01) + (p02 + p03);
            rs[1] += (p10 + p11) + (p12 + p13);
            pa0.u[mtk * 2]     = cvt_pk_bf16(p00, p01);
            pa0.u[mtk * 2 + 1] = cvt_pk_bf16(p02, p03);
            pa1.u[mtk * 2]     = cvt_pk_bf16(p10, p11);
            pa1.u[mtk * 2 + 1] = cvt_pk_bf16(p12, p13);
        }

        // O += P V   (A-frag = lane-local packed P, B-frag = sigma-ordered V)
#pragma unroll
        for (int ks = 0; ks < 2; ++ks) {
            short8 bf[4];
#pragma unroll
            for (int nt = 0; nt < 4; ++nt)
                bf[nt] = *(const short8*)&Vl[(nt * 16 + l16) * 72 + ks * 32 + quad * 8];
            short8 af0 = pa0.h[ks];
            short8 af1 = pa1.h[ks];
            __builtin_amdgcn_s_setprio(1);
#pragma unroll
            for (int nt = 0; nt < 4; ++nt)
                o[0][nt] = __builtin_amdgcn_mfma_f32_16x16x32_bf16(af0, bf[nt], o[0][nt], 0, 0, 0);
#pragma unroll
            for (int nt = 0; nt < 4; ++nt)
                o[1][nt] = __builtin_amdgcn_mfma_f32_16x16x32_bf16(af1, bf[nt], o[1][nt], 0, 0, 0);
            __builtin_amdgcn_s_setprio(0);
        }
    }

    // row-sums: lane partial covers its 4 quads' kv rows -> reduce over quads only
#pragma unroll
    for (int ntq = 0; ntq < 2; ++ntq) {
        rs[ntq] += __shfl_xor(rs[ntq], 16);
        rs[ntq] += __shfl_xor(rs[ntq], 32);
    }

#pragma unroll
    for (int ntq = 0; ntq < 2; ++ntq) {
#pragma unroll
        for (int nt = 0; nt < 4; ++nt)
#pragma unroll
            for (int r = 0; r < 4; ++r) {
                int qrow = q0 + wave * 32 + ntq * 16 + quad * 4 + r;
                Opart[((size_t)sp * 16384 + bS + qrow) * 64 + nt * 16 + l16] = o[ntq][nt][r];
            }
        if (quad == 0)
            Ll[(size_t)sp * 16384 + bS + q0 + wave * 32 + ntq * 16 + l16] = rs[ntq];
    }
}

// ---------------- kernel 3: combine kv-split partials (no exp needed) --------
__global__ void combine_kernel(const float* __restrict__ Opart, const float* __restrict__ Ll,
                               float* __restrict__ out, int nsplit) {
    int idx = blockIdx.x * 256 + threadIdx.x;   // 1048576 outputs
    int q = idx >> 6;
    float den = 0.f, num = 0.f;
    for (int s = 0; s < nsplit; ++s) {
        den += Ll[s * 16384 + q];
        num += Opart[(size_t)s * 1048576 + idx];
    }
    out[idx] = num / den;
}

extern "C" void kernel_launch(void* const* d_in, const int* in_sizes, int n_in,
                              void* d_out, int out_size, void* d_ws, size_t ws_size,
                              hipStream_t stream) {
    const float* x  = (const float*)d_in[0];
    const float* Wk = (const float*)d_in[1];
    const float* Wq = (const float*)d_in[2];
    const float* Wv = (const float*)d_in[3];
    float* out = (float*)d_out;

    char* w = (char*)d_ws;
    size_t off = 0;
    auto take = [&](size_t bytes) -> void* {
        void* p = w + off;
        off = (off + bytes + 255) & ~(size_t)255;
        return p;
    };
    short* Qs  = (short*)take((size_t)16384 * 64 * 2);
    short* Kb  = (short*)take((size_t)16384 * 64 * 2);
    short* Vt  = (short*)take((size_t)16384 * 64 * 2);
    short* Wt3 = (short*)take((size_t)3 * 64 * 768 * 2);

    size_t base = off;
    int nsplit = 8;         // QBLK=128 -> grid (32,4,8) = 1024 blocks -> 4/CU candidate
    while (nsplit > 1) {
        size_t need = base + (((size_t)nsplit * 16384 * 4 + 255) & ~(size_t)255)
                      + (size_t)nsplit * 16384 * 64 * 4 + 512;
        if (need <= ws_size) break;
        nsplit >>= 1;
    }
    float* Ll    = (float*)take((size_t)nsplit * 16384 * 4);
    float* Opart = (float*)take((size_t)nsplit * 16384 * 64 * 4);

    wtrans_kernel<<<576, 256, 0, stream>>>(Wk, Wq, Wv, Wt3);
    proj_kernel<<<1024, 256, 0, stream>>>(x, Wt3, Qs, Kb, Vt);
    dim3 ag(32, 4, nsplit);
    attn_kernel<<<ag, 256, 0, stream>>>(Qs, Kb, Vt, Opart, Ll, 4096 / nsplit);
    combine_kernel<<<4096, 256, 0, stream>>>(Opart, Ll, out, nsplit);
}